// Round 9
// baseline (3483.587 us; speedup 1.0000x reference)
//
#include <hip/hip_runtime.h>

#define NG 8     // independent batch groups (16 rows each)
#define NR 12    // block roles per group: 0..7 layer1, 8..11 layer2

// Epoch flag per (group, role), each on its own 128 B line. Monotonic:
// flag = 1 after publishing the step(-1) zeros, s+2 after publishing step s.
// Zeroed by init_kernel (stream-ordered before the main kernel).
__device__ unsigned int g_flag[NG * NR * 32];

typedef __attribute__((ext_vector_type(8))) short short8;
typedef __attribute__((ext_vector_type(4))) float floatx4;

// Split fp32 v into bf16 hi + bf16 lo (residual), packed (hi<<16)|lo.
__device__ __forceinline__ unsigned int split_pack(float v) {
    unsigned int u  = __float_as_uint(v);
    unsigned int hb = u & 0xffff0000u;          // truncated-bf16 hi, exact in fp32
    float r = v - __uint_as_float(hb);          // exact residual
    return hb | (__float_as_uint(r) >> 16);
}

__device__ __forceinline__ float sigmoidf_(float z) {
    return 1.0f / (1.0f + __expf(-z));
}

// 32 B of packed h via 4 returning 8-byte atomic RMWs (add 0). Atomic RMWs
// execute AT the device coherence point (m20-verified cross-XCD coherent) —
// cannot read stale cache lines, no fences needed.
__device__ __forceinline__ void unpack_rmw(unsigned int* hp, short8& ah, short8& al) {
    unsigned long long* q = (unsigned long long*)hp;
    unsigned long long q0 = atomicAdd(q + 0, 0ULL), q1 = atomicAdd(q + 1, 0ULL),
                       q2 = atomicAdd(q + 2, 0ULL), q3 = atomicAdd(q + 3, 0ULL);
    unsigned int pv[8] = {(unsigned)q0, (unsigned)(q0 >> 32), (unsigned)q1, (unsigned)(q1 >> 32),
                          (unsigned)q2, (unsigned)(q2 >> 32), (unsigned)q3, (unsigned)(q3 >> 32)};
#pragma unroll
    for (int j = 0; j < 8; ++j) {
        ah[j] = (short)(pv[j] >> 16);
        al[j] = (short)(pv[j] & 0xffffu);
    }
}

__device__ __forceinline__ void cvt_x8(const float* xv, short8& ah, short8& al) {
#pragma unroll
    for (int j = 0; j < 8; ++j) {
        unsigned int u  = __float_as_uint(xv[j]);
        unsigned int hb = u & 0xffff0000u;
        float r = xv[j] - __uint_as_float(hb);
        ah[j] = (short)(u >> 16);
        al[j] = (short)(__float_as_uint(r) >> 16);
    }
}

// Wait until layer1 flags >= need1 (lanes 0..7) and layer2 flags >= need2
// (lanes 8..11). Poll via returning atomic RMW (executes at LLC — always
// current). __syncthreads orders all waves' subsequent data RMWs after poll.
__device__ __forceinline__ void wait_deps(unsigned int* fbase, int need1, int need2) {
    if (threadIdx.x < NR) {
        unsigned int* f = fbase + threadIdx.x * 32;
        int need = (threadIdx.x < 8) ? need1 : need2;
        while ((int)atomicAdd(f, 0u) < need) {}
    }
    __syncthreads();
}

// Publish: drain own data RMWs (vmcnt ack from the TCC that executed them),
// block-sync so ALL waves' data is at LLC, then thread 0 RMWs the flag.
__device__ __forceinline__ void publish(unsigned int* myflag, unsigned int epoch) {
    asm volatile("s_waitcnt vmcnt(0)" ::: "memory");
    __syncthreads();
    if (threadIdx.x == 0) (void)atomicExch(myflag, epoch);
}

// One LSTM layer role for one batch group (16 rows). Wave owns the group's
// m-tile x 2 column-tiles (8 units, all 4 gates). Weights pre-split to bf16
// hi/lo MFMA B-fragments in registers.
// KX = number of K-columns taken from Wm (the rest from Um). L1: 64, L2: 256.
// (R7/R8 bug: KX was 0 for L2 -> all weights read from U2 incl. OOB rows.)
// MFMA 16x16x32_bf16: A: m=lane&15,k=quad*8+j ; D: col=lane&15, row=quad*4+r
// Flags/buffering: h1 quad-buffered (slot s&3), h2 double-buffered (slot s&1).
//  L1 step s: waits fL1 >= s+1 (h1[s-1]) and fL2 >= s-2 (slot-reuse safety).
//  L2 step s: waits fL1 >= s+2 (h1[s]) and fL2 >= s+1 (h2[s-1]).
template<int NKC, int KX, int GW, int UU, bool L1>
__device__ void lstm_role(const float* __restrict__ x,
                          const float* __restrict__ Wm, const float* __restrict__ Um,
                          const float* __restrict__ bias,
                          unsigned int* __restrict__ h1pk, unsigned int* __restrict__ h2pk,
                          float* __restrict__ out,
                          unsigned int* __restrict__ myflag,
                          unsigned int* __restrict__ fbase,
                          int m0, int wid, float (*zex)[17])
{
    const int lane = threadIdx.x & 63;
    const int n    = lane & 15;
    const int quad = lane >> 4;
    const int gate = n >> 2;
    const int u0   = wid * 8;             // 8 units per wave (2 coltiles x 4)
    const int arow = m0 + n;              // A-fragment row this lane loads
    const int b_l  = lane >> 2;           // epilogue: batch-local 0..15
    const int ul   = lane & 3;            // epilogue: unit-local 0..3

    // ---- one-time: weight B-fragments (hi/lo split), bias ----
    short8 bh[2][NKC], bl[2][NKC];
    float bias_v[2];
#pragma unroll
    for (int c = 0; c < 2; ++c) {
        const int col = gate * UU + u0 + c * 4 + (n & 3);
        bias_v[c] = bias[col];
#pragma unroll
        for (int kc = 0; kc < NKC; ++kc) {
#pragma unroll
            for (int j = 0; j < 8; ++j) {
                int k = kc * 32 + quad * 8 + j;
                float w = (k < KX) ? Wm[k * GW + col] : Um[(k - KX) * GW + col];
                unsigned int p = split_pack(w);
                bh[c][kc][j] = (short)(p >> 16);
                bl[c][kc][j] = (short)(p & 0xffffu);
            }
        }
    }

    // ---- publish the step(-1) zeros (h1 slot 3 / h2 slot 1), flag = 1 ----
#pragma unroll
    for (int c = 0; c < 2; ++c) {
        if (L1) (void)atomicExch(&h1pk[3 * 32768 + (m0 + b_l) * 256 + u0 + c * 4 + ul], 0u);
        else    (void)atomicExch(&h2pk[1 * 16384 + (m0 + b_l) * 128 + u0 + c * 4 + ul], 0u);
    }
    float cst[2] = {0.f, 0.f};
    publish(myflag, 1u);

    for (int s = 0; s < 512; ++s) {
        // ---- prefetch x[s] (plain cached loads; x is read-only) ----
        float xv[16];
        if (L1) {
            const float* xsrc = x + (size_t)arow * (512 * 64) + s * 64 + quad * 8;
            float4 a0 = *(const float4*)(xsrc);
            float4 a1 = *(const float4*)(xsrc + 4);
            float4 a2 = *(const float4*)(xsrc + 32);
            float4 a3 = *(const float4*)(xsrc + 36);
            xv[0]=a0.x; xv[1]=a0.y; xv[2]=a0.z;  xv[3]=a0.w;
            xv[4]=a1.x; xv[5]=a1.y; xv[6]=a1.z;  xv[7]=a1.w;
            xv[8]=a2.x; xv[9]=a2.y; xv[10]=a2.z; xv[11]=a2.w;
            xv[12]=a3.x; xv[13]=a3.y; xv[14]=a3.z; xv[15]=a3.w;
        }

        // ---- wait for dependencies of step s ----
        if (L1) wait_deps(fbase, s + 1, s - 2);
        else    wait_deps(fbase, s + 2, s + 1);

        floatx4 acc[2];
#pragma unroll
        for (int c = 0; c < 2; ++c)
            acc[c] = {bias_v[c], bias_v[c], bias_v[c], bias_v[c]};

        unsigned int* hA = L1
            ? (h1pk + ((s + 3) & 3) * 32768 + arow * 256)    // h1[s-1]
            : (h1pk + (s & 3) * 32768 + arow * 256);         // h1[s]
        unsigned int* hB = L1
            ? nullptr
            : (h2pk + ((s + 1) & 1) * 16384 + arow * 128);   // h2[s-1]

#pragma unroll
        for (int kc = 0; kc < NKC; ++kc) {
            short8 ah, al;
            if (L1) {
                if (kc < 2) cvt_x8(xv + kc * 8, ah, al);
                else        unpack_rmw(hA + (kc - 2) * 32 + quad * 8, ah, al);
            } else {
                if (kc < 8) unpack_rmw(hA + kc * 32 + quad * 8, ah, al);
                else        unpack_rmw(hB + (kc - 8) * 32 + quad * 8, ah, al);
            }
#pragma unroll
            for (int c = 0; c < 2; ++c) {
                acc[c] = __builtin_amdgcn_mfma_f32_16x16x32_bf16(ah, bh[c][kc], acc[c], 0, 0, 0);
                acc[c] = __builtin_amdgcn_mfma_f32_16x16x32_bf16(ah, bl[c][kc], acc[c], 0, 0, 0);
                acc[c] = __builtin_amdgcn_mfma_f32_16x16x32_bf16(al, bh[c][kc], acc[c], 0, 0, 0);
            }
        }

        // ---- epilogue: gate-gather via per-wave LDS tile, LSTM cell update,
        // publish h via atomicExch (executes at LLC, coherent). ----
#pragma unroll
        for (int c = 0; c < 2; ++c) {
#pragma unroll
            for (int r = 0; r < 4; ++r) zex[quad * 4 + r][n] = acc[c][r];
            asm volatile("s_waitcnt lgkmcnt(0)" ::: "memory");
            float zi = zex[b_l][ 0 + ul];
            float zf = zex[b_l][ 4 + ul];
            float zg = zex[b_l][ 8 + ul];
            float zo = zex[b_l][12 + ul];
            asm volatile("s_waitcnt lgkmcnt(0)" ::: "memory");
            float ig = sigmoidf_(zi);
            float fg = sigmoidf_(zf);
            float gg = fmaxf(zg, 0.f);
            float og = sigmoidf_(zo);
            cst[c] = fg * cst[c] + ig * gg;
            float h = og * fmaxf(cst[c], 0.f);
            unsigned int p = split_pack(h);
            int b = m0 + b_l;
            if (L1) {
                (void)atomicExch(&h1pk[(s & 3) * 32768 + b * 256 + u0 + c * 4 + ul], p);
            } else {
                (void)atomicExch(&h2pk[(s & 1) * 16384 + b * 128 + u0 + c * 4 + ul], p);
                if (s == 511) out[b * 128 + u0 + c * 4 + ul] = h;   // plain store
            }
        }
        publish(myflag, (unsigned)(s + 2));
    }
}

__global__ void __launch_bounds__(256, 1)
lstm_fused_kernel(const float* __restrict__ x,
                  const float* __restrict__ W1, const float* __restrict__ U1,
                  const float* __restrict__ b1,
                  const float* __restrict__ W2, const float* __restrict__ U2,
                  const float* __restrict__ b2,
                  float* __restrict__ out, unsigned int* __restrict__ ws)
{
    __shared__ float zex[4][16][17];       // per-wave gate-gather tiles
    unsigned int* h1pk = ws;               // [4][128][256] packed hi/lo bf16 (quad-buffer)
    unsigned int* h2pk = ws + 131072;      // [2][128][128] (double-buffer)
    const int g    = blockIdx.x & 7;       // batch group
    const int role = blockIdx.x >> 3;      // 0..7 layer1, 8..11 layer2
    const int wv   = threadIdx.x >> 6;
    const int m0   = g * 16;
    unsigned int* fbase  = &g_flag[g * NR * 32];
    unsigned int* myflag = fbase + role * 32;
    if (role < 8) {
        // layer1: 8 blocks x 4 waves = 32 unit-waves x 8 units = 256 units
        // K = 64 (x via W1) + 256 (h1 via U1)
        lstm_role<10, 64, 1024, 256, true >(x, W1, U1, b1, h1pk, h2pk, out,
                                            myflag, fbase, m0, role * 4 + wv, zex[wv]);
    } else {
        // layer2: 4 blocks x 4 waves = 16 unit-waves x 8 units = 128 units
        // K = 256 (h1 via W2) + 128 (h2 via U2)
        lstm_role<12, 256, 512, 128, false>(x, W2, U2, b2, h1pk, h2pk, out,
                                            myflag, fbase, m0, (role - 8) * 4 + wv, zex[wv]);
    }
}

// Pre-kernel (plain launch): zero epoch flags, write diagnostic sentinel.
// Failure signatures: absmax~7 => main never ran; absmax~0.162 => main ran
// but h propagation broken (all-zero h path); other => partial staleness.
__global__ void init_kernel(float* __restrict__ out) {
    int t = blockIdx.x * 256 + threadIdx.x;
    if (t < NG * NR * 32) g_flag[t] = 0u;
    if (t < 16384) out[t] = 7.0f;
}

extern "C" void kernel_launch(void* const* d_in, const int* in_sizes, int n_in,
                              void* d_out, int out_size, void* d_ws, size_t ws_size,
                              hipStream_t stream) {
    const float* x  = (const float*)d_in[0];
    const float* W1 = (const float*)d_in[1];
    const float* U1 = (const float*)d_in[2];
    const float* b1 = (const float*)d_in[3];
    const float* W2 = (const float*)d_in[4];
    const float* U2 = (const float*)d_in[5];
    const float* b2 = (const float*)d_in[6];
    float* out = (float*)d_out;
    unsigned int* ws = (unsigned int*)d_ws;
    init_kernel<<<64, 256, 0, stream>>>(out);
    lstm_fused_kernel<<<96, 256, 0, stream>>>(x, W1, U1, b1, W2, U2, b2, out, ws);
}